// Round 8
// baseline (300.041 us; speedup 1.0000x reference)
//
#include <hip/hip_runtime.h>
#include <stdint.h>

#define N_BANK 200000
#define N_PAD  201600          // 3150 steps * 64 cols
#define NQ     2048
#define DIMD   128
#define C_IN   112
#define NCB    32              // column blocks (98 or 99 64-col steps each)
#define NCE    64              // NCB * 2 wave-col halves
#define NC3    192             // NCE * 3
#define PREP_BANK_BLK 2048     // grid-stride bank-norm blocks
#define PREP_EMB_BLK  1024     // 2048 queries / 2 per block

typedef short v8s __attribute__((ext_vector_type(8)));
typedef float v4f __attribute__((ext_vector_type(4)));

typedef const __attribute__((address_space(1))) uint32_t* gp1_t;
typedef __attribute__((address_space(3))) uint32_t* lp3_t;

__device__ __forceinline__ void async16(const void* g, void* l) {
  __builtin_amdgcn_global_load_lds((gp1_t)g, (lp3_t)l, 16, 0, 0);
}

__device__ __forceinline__ unsigned short f2bf(float f) {
  uint32_t u = __float_as_uint(f);
  u += 0x7fff + ((u >> 16) & 1);   // round-to-nearest-even
  return (unsigned short)(u >> 16);
}

// running top-3 insert: 3 independent VALU ops (all read OLD state)
__device__ __forceinline__ void insert3(float& m1, float& m2, float& m3, float v) {
  m3 = __builtin_amdgcn_fmed3f(m2, m3, v);
  m2 = __builtin_amdgcn_fmed3f(m1, m2, v);
  m1 = fmaxf(m1, v);
}

// ---------------- kernel 1: fused prep = bank L2 norm + patch embedding ----
// blocks [0, 2048): grid-stride over bank rows (4 rows/wave-iter, ~25 iters)
// blocks [2048, 3072): 2 queries each (proj + L2 norm -> bf16, same swizzle)
__global__ void prep_kernel(const float* __restrict__ fm, const float* __restrict__ pw,
                            const float* __restrict__ bank,
                            unsigned short* __restrict__ embB,
                            unsigned short* __restrict__ bankB) {
  int blk = blockIdx.x;
  int tid = threadIdx.x;
  if (blk < PREP_BANK_BLK) {
    // ---- bank part: one row per wave per iteration ----
    int wv = tid >> 6, lane = tid & 63;
    uint32_t* out = (uint32_t*)bankB;     // packed 2x bf16
    int j = lane >> 2, w = lane & 3;      // 16B block, dword within
    for (int r = blk * 4 + wv; r < N_PAD; r += PREP_BANK_BLK * 4) {
      int sdw = ((j ^ (r & 15)) << 2) | w;  // swizzled dword index in row
      if (r < N_BANK) {
        float2 v = ((const float2*)bank)[r * 64 + lane];
        float s = v.x * v.x + v.y * v.y;
#pragma unroll
        for (int off = 32; off; off >>= 1) s += __shfl_xor(s, off);
        float scale = 1.f / fmaxf(sqrtf(s), 1e-12f);
        uint32_t lo = f2bf(v.x * scale);
        uint32_t hi = f2bf(v.y * scale);
        out[r * 64 + sdw] = lo | (hi << 16);
      } else {
        out[r * 64 + sdw] = 0u;
      }
    }
  } else {
    // ---- emb part: 2 queries per block (128 threads each) ----
    __shared__ float x[2][C_IN];
    __shared__ float wsum[4];
    int half = tid >> 7;                 // which query in this block
    int t = tid & 127;                   // output dim 0..127
    int q = (blk - PREP_BANK_BLK) * 2 + half; // 0..2047
    int b = q >> 8, p = q & 255;
    if (t < C_IN) x[half][t] = fm[(b * C_IN + t) * 256 + p];
    __syncthreads();
    const float* row = pw + t * C_IN;
    float dot = 0.f;
#pragma unroll
    for (int c = 0; c < C_IN; ++c) dot = fmaf(x[half][c], row[c], dot);
    float s = dot * dot;
#pragma unroll
    for (int off = 32; off; off >>= 1) s += __shfl_xor(s, off);
    int wv = tid >> 6, lane = tid & 63;
    if (lane == 0) wsum[wv] = s;
    __syncthreads();
    float ss = wsum[half * 2] + wsum[half * 2 + 1];
    float scale = 1.f / fmaxf(sqrtf(ss), 1e-12f);
    int j = t >> 3, pos = t & 7;                     // 16B block, elem within
    int sw = j ^ (q & 15);                           // bank-conflict swizzle
    embB[q * DIMD + sw * 8 + pos] = f2bf(dot * scale);
  }
}

// ---------------- kernel 2: fused sims GEMM + running top-3 -----------------
// OCCUPANCY REDESIGN. Counter arithmetic across rounds 2/5/6/7: MFMA pipe
// demand = 35% of wall, true VALU = ~18% (VALUBusy counts MFMA issue slots),
// SIMD idle ~47% -- stall-coverage-bound at 2 waves/SIMD. The 2-wave cap was
// the unified reg file: arch ~84-88 VGPR + 64 AGPR (a[4][4]) ~= 150 regs.
// Fix: 512-thread blocks, 8 waves in 4x2; each wave 32 rows x 32 cols:
//   a[2][4] = 32 regs, m-state 24, acc 8 -> ~110 unified <= 128
//   -> 4 waves/SIMD (2 blocks/CU x 8 waves), double stall coverage.
// Inner body = proven round-5/6 2-barrier schedule, unchanged semantics:
// issue-next-first, counted vmcnt(2), (s&1) LDS addressing, no setprio.
// Grid 512 = 32 cbs x 16 M-tiles (98/99 steps of 64 cols), XCD-grouped.
__global__ __launch_bounds__(512, 4)
void sim_top3_kernel(const unsigned short* __restrict__ embB,
                     const unsigned short* __restrict__ bankB,
                     float* __restrict__ partial) {
  int id = blockIdx.x;                 // 0..511
  int x = id & 7, j = id >> 3;         // XCD, 0..63
  int cb = x * 4 + (j >> 4);           // column block 0..31
  int mt = j & 15;                     // M tile
  // 3150 total 64-col steps: 14 cbs of 99, 18 cbs of 98
  int start = (cb < 14) ? 99 * cb : 1386 + 98 * (cb - 14);
  int nsteps = (cb < 14) ? 99 : 98;
  int q0 = mt * 128;
  int tid = threadIdx.x;
  int wv = tid >> 6, lane = tid & 63;
  int wr = wv >> 1, wc = wv & 1;       // wave row(0..3)/col(0..1) in 4x2
  int g = lane >> 4, c0 = lane & 15;   // frag k-group / col-class

  __shared__ __align__(16) unsigned char lds[32768];   // 2 x 16 KB B buffers

  // ---- stage A tile (128 rows x 128 K, bf16, swizzled) across both bufs ----
  {
    const char* gbase = (const char*)embB + q0 * 256;
#pragma unroll
    for (int i = 0; i < 4; ++i) {
      int off = i * 8192 + tid * 16;
      async16(gbase + off, lds + off);
    }
  }
  asm volatile("s_waitcnt vmcnt(0)" ::: "memory");
  __builtin_amdgcn_sched_barrier(0);
  __builtin_amdgcn_s_barrier();

  // ---- hoist A fragments to registers (32 VGPRs), persistent all steps ----
  v8s a[2][4];
#pragma unroll
  for (int fm = 0; fm < 2; ++fm)
#pragma unroll
    for (int k = 0; k < 4; ++k) {
      int row = wr * 32 + fm * 16 + c0;
      a[fm][k] = *(const v8s*)(lds + row * 256 + (((k * 4 + g) ^ c0) << 4));
    }
  // all waves must finish reading A before B staging overwrites the buffers
  asm volatile("s_waitcnt lgkmcnt(0)" ::: "memory");
  __builtin_amdgcn_sched_barrier(0);
  __builtin_amdgcn_s_barrier();

  float m1[8], m2[8], m3[8];
#pragma unroll
  for (int t = 0; t < 8; ++t) { m1[t] = -1e30f; m2[t] = -1e30f; m3[t] = -1e30f; }
  const v4f vzero = {0.f, 0.f, 0.f, 0.f};   // shared acc-init regs, hoisted

  const char* bbase = (const char*)bankB + (size_t)start * 16384;  // 64 cols * 256 B

  // ---- prologue: stage step 0 into buf0 (2 async16/thread = 16 KB/block) ----
#pragma unroll
  for (int i = 0; i < 2; ++i) {
    int off = i * 8192 + tid * 16;
    async16(bbase + off, lds + off);
  }

  const char* gnext = bbase + 16384;   // running pointer: step s+1 source
  for (int s = 0; s < nsteps; ++s) {
    if (s + 1 < nsteps) {
      // issue next-step stage FIRST, then wait only for the current buffer
      unsigned char* ldst = lds + ((s + 1) & 1) * 16384;
#pragma unroll
      for (int i = 0; i < 2; ++i) {
        int off = i * 8192 + tid * 16;
        async16(gnext + off, ldst + off);
      }
      gnext += 16384;
      asm volatile("s_waitcnt vmcnt(2)" ::: "memory");  // prefetch stays in flight
    } else {
      asm volatile("s_waitcnt vmcnt(0)" ::: "memory");  // epilogue: drain last buffer
    }
    __builtin_amdgcn_sched_barrier(0);
    __builtin_amdgcn_s_barrier();                       // buf[cur] ready across waves

    const unsigned char* bp = lds + (s & 1) * 16384;
#pragma unroll
    for (int fn = 0; fn < 2; ++fn) {
      v8s bf[4];
      int col = wc * 32 + fn * 16 + c0;
#pragma unroll
      for (int k = 0; k < 4; ++k)
        bf[k] = *(const v8s*)(bp + col * 256 + (((k * 4 + g) ^ c0) << 4));
      v4f acc0 = __builtin_amdgcn_mfma_f32_16x16x32_bf16(a[0][0], bf[0], vzero, 0, 0, 0);
      v4f acc1 = __builtin_amdgcn_mfma_f32_16x16x32_bf16(a[1][0], bf[0], vzero, 0, 0, 0);
#pragma unroll
      for (int k = 1; k < 4; ++k) {
        acc0 = __builtin_amdgcn_mfma_f32_16x16x32_bf16(a[0][k], bf[k], acc0, 0, 0, 0);
        acc1 = __builtin_amdgcn_mfma_f32_16x16x32_bf16(a[1][k], bf[k], acc1, 0, 0, 0);
      }
#pragma unroll
      for (int j2 = 0; j2 < 4; ++j2) {   // C/D: row=g*4+j2, col=c0 (within frag)
        insert3(m1[j2], m2[j2], m3[j2], acc0[j2]);
        insert3(m1[4 + j2], m2[4 + j2], m3[4 + j2], acc1[j2]);
      }
    }
    // all waves done reading buf[cur] before next iteration overwrites it
    __builtin_amdgcn_s_barrier();
  }

  // ---- merge top-3 across the 16 col-class lanes (butterfly) ----
#pragma unroll
  for (int mask = 1; mask < 16; mask <<= 1) {
#pragma unroll
    for (int t = 0; t < 8; ++t) {
      float v1 = __shfl_xor(m1[t], mask);
      float v2 = __shfl_xor(m2[t], mask);
      float v3 = __shfl_xor(m3[t], mask);
      insert3(m1[t], m2[t], m3[t], v1);
      insert3(m1[t], m2[t], m3[t], v2);
      insert3(m1[t], m2[t], m3[t], v3);
    }
  }

  if (c0 == 0) {
    int ce = cb * 2 + wc;                // per wave-col half partials, 0..63
#pragma unroll
    for (int t = 0; t < 8; ++t) {        // t = fm*4 + j2
      int q = q0 + wr * 32 + (t >> 2) * 16 + g * 4 + (t & 3);
      float* dst = partial + (size_t)q * NC3 + ce * 3;   // query-major
      dst[0] = m1[t];
      dst[1] = m2[t];
      dst[2] = m3[t];
    }
  }
}

// ---------------- kernel 3: fused final = per-query merge + top-8 mean ------
// one block per image; thread q' owns query b*256+q' (scan 192 partials,
// top-3 -> distance), then in-block top-8 tree over the 256 distances.
__global__ void final_kernel(const float* __restrict__ partial, float* __restrict__ out) {
  int b = blockIdx.x;            // image
  int tid = threadIdx.x;         // patch 0..255
  int q = b * 256 + tid;
  const float* src = partial + (size_t)q * NC3;
  float m1 = -1e30f, m2 = -1e30f, m3 = -1e30f;
  for (int c = 0; c < NC3; ++c) insert3(m1, m2, m3, src[c]);
  float d1 = sqrtf(fmaxf(2.f - 2.f * m1, 0.f));
  float d2 = sqrtf(fmaxf(2.f - 2.f * m2, 0.f));
  float d3 = sqrtf(fmaxf(2.f - 2.f * m3, 0.f));
  float d = (d1 + d2 + d3) * (1.f / 3.f);

  __shared__ float vals[256];
  __shared__ float rv[256];
  __shared__ int ri[256];
  vals[tid] = d;
  __syncthreads();
  float sum = 0.f;
  for (int iter = 0; iter < 8; ++iter) {   // k = ceil(256*0.03) = 8
    rv[tid] = vals[tid]; ri[tid] = tid;
    __syncthreads();
    for (int s = 128; s > 0; s >>= 1) {
      if (tid < s && rv[tid + s] > rv[tid]) { rv[tid] = rv[tid + s]; ri[tid] = ri[tid + s]; }
      __syncthreads();
    }
    sum += rv[0];
    if (tid == 0) vals[ri[0]] = -1e30f;
    __syncthreads();
  }
  if (tid == 0) out[b] = sum * (1.f / 8.f);
}

extern "C" void kernel_launch(void* const* d_in, const int* in_sizes, int n_in,
                              void* d_out, int out_size, void* d_ws, size_t ws_size,
                              hipStream_t stream) {
  const float* fm   = (const float*)d_in[0];   // [8,112,16,16]
  const float* pw   = (const float*)d_in[1];   // [128,112]
  const float* bank = (const float*)d_in[2];   // [200000,128]
  float* out = (float*)d_out;                  // [8]

  char* ws = (char*)d_ws;
  unsigned short* bankB = (unsigned short*)ws;                       // 51,609,600 B
  unsigned short* embB  = (unsigned short*)(ws + 51609600);          //    524,288 B
  float* partial        = (float*)(ws + 51609600 + 524288);          //  1,572,864 B

  prep_kernel<<<PREP_BANK_BLK + PREP_EMB_BLK, 256, 0, stream>>>(fm, pw, bank, embB, bankB);
  sim_top3_kernel<<<512, 512, 0, stream>>>(embB, bankB, partial);
  final_kernel<<<8, 256, 0, stream>>>(partial, out);
}

// Round 9
// 283.762 us; speedup vs baseline: 1.0574x; 1.0574x over previous
//
#include <hip/hip_runtime.h>
#include <stdint.h>

#define N_BANK 200000
#define N_PAD  201600          // 3150 steps * 64 cols
#define NQ     2048
#define DIMD   128
#define C_IN   112
#define NCB    64              // column blocks (49 or 50 64-col steps each)
#define NC3    192             // NCB * 3
#define PREP_BANK_BLK 2048     // grid-stride bank-norm blocks
#define PREP_EMB_BLK  1024     // 2048 queries / 2 per block

typedef short v8s __attribute__((ext_vector_type(8)));
typedef float v4f __attribute__((ext_vector_type(4)));

typedef const __attribute__((address_space(1))) uint32_t* gp1_t;
typedef __attribute__((address_space(3))) uint32_t* lp3_t;

__device__ __forceinline__ void async16(const void* g, void* l) {
  __builtin_amdgcn_global_load_lds((gp1_t)g, (lp3_t)l, 16, 0, 0);
}

__device__ __forceinline__ unsigned short f2bf(float f) {
  uint32_t u = __float_as_uint(f);
  u += 0x7fff + ((u >> 16) & 1);   // round-to-nearest-even
  return (unsigned short)(u >> 16);
}

// running top-3 insert: 3 independent VALU ops (all read OLD state)
__device__ __forceinline__ void insert3(float& m1, float& m2, float& m3, float v) {
  m3 = __builtin_amdgcn_fmed3f(m2, m3, v);
  m2 = __builtin_amdgcn_fmed3f(m1, m2, v);
  m1 = fmaxf(m1, v);
}

// ---------------- kernel 1: fused prep = bank L2 norm + patch embedding ----
// blocks [0, 2048): grid-stride over bank rows (4 rows/wave-iter, ~25 iters)
// blocks [2048, 3072): 2 queries each (proj + L2 norm -> bf16, same swizzle)
__global__ void prep_kernel(const float* __restrict__ fm, const float* __restrict__ pw,
                            const float* __restrict__ bank,
                            unsigned short* __restrict__ embB,
                            unsigned short* __restrict__ bankB) {
  int blk = blockIdx.x;
  int tid = threadIdx.x;
  if (blk < PREP_BANK_BLK) {
    // ---- bank part: one row per wave per iteration ----
    int wv = tid >> 6, lane = tid & 63;
    uint32_t* out = (uint32_t*)bankB;     // packed 2x bf16
    int j = lane >> 2, w = lane & 3;      // 16B block, dword within
    for (int r = blk * 4 + wv; r < N_PAD; r += PREP_BANK_BLK * 4) {
      int sdw = ((j ^ (r & 15)) << 2) | w;  // swizzled dword index in row
      if (r < N_BANK) {
        float2 v = ((const float2*)bank)[r * 64 + lane];
        float s = v.x * v.x + v.y * v.y;
#pragma unroll
        for (int off = 32; off; off >>= 1) s += __shfl_xor(s, off);
        float scale = 1.f / fmaxf(sqrtf(s), 1e-12f);
        uint32_t lo = f2bf(v.x * scale);
        uint32_t hi = f2bf(v.y * scale);
        out[r * 64 + sdw] = lo | (hi << 16);
      } else {
        out[r * 64 + sdw] = 0u;
      }
    }
  } else {
    // ---- emb part: 2 queries per block (128 threads each) ----
    __shared__ float x[2][C_IN];
    __shared__ float wsum[4];
    int half = tid >> 7;                 // which query in this block
    int t = tid & 127;                   // output dim 0..127
    int q = (blk - PREP_BANK_BLK) * 2 + half; // 0..2047
    int b = q >> 8, p = q & 255;
    if (t < C_IN) x[half][t] = fm[(b * C_IN + t) * 256 + p];
    __syncthreads();
    const float* row = pw + t * C_IN;
    float dot = 0.f;
#pragma unroll
    for (int c = 0; c < C_IN; ++c) dot = fmaf(x[half][c], row[c], dot);
    float s = dot * dot;
#pragma unroll
    for (int off = 32; off; off >>= 1) s += __shfl_xor(s, off);
    int wv = tid >> 6, lane = tid & 63;
    if (lane == 0) wsum[wv] = s;
    __syncthreads();
    float ss = wsum[half * 2] + wsum[half * 2 + 1];
    float scale = 1.f / fmaxf(sqrtf(ss), 1e-12f);
    int j = t >> 3, pos = t & 7;                     // 16B block, elem within
    int sw = j ^ (q & 15);                           // bank-conflict swizzle
    embB[q * DIMD + sw * 8 + pos] = f2bf(dot * scale);
  }
}

// ---------------- kernel 2: fused sims GEMM + running top-3 -----------------
// STAGING-BANDWIDTH REDESIGN. Evidence across rounds 2/5-8: every schedule/
// occupancy/tiling landed at ~130 us staging 825 MB of B tiles (16 M-tiles x
// 51.6 MB) = 6.35 TB/s = the measured full-chip load-path ceiling (m13);
// per-step walls in r6/r8 are predicted within 3% by staged-bytes/10.3 B/cy/CU.
// Fix: M-tile 512 (4 M-tiles) -> staged B = 206 MB, under the 51-us MFMA floor.
//   grid 256 = 64 cbs x 4 M-tiles, 1 block/CU, one clean round, XCD-grouped
//   512 threads = 8 waves; wave owns 64 rows x all 64 step-cols:
//   a[4][4]=64 VGPR + m-state 48 + bf/acc/addr ~= 160 -> 2 waves/SIMD at
//   bounds(512,2) cap 256 (no spill; occupancy proven irrelevant in r8).
// A-tile (512 rows = 128 KB) staged in 4 x 32 KB LDS rounds, then B loop =
// the proven r8 2-barrier counted-vmcnt body with fn 0..3.
__global__ __launch_bounds__(512, 2)
void sim_top3_kernel(const unsigned short* __restrict__ embB,
                     const unsigned short* __restrict__ bankB,
                     float* __restrict__ partial) {
  int id = blockIdx.x;                 // 0..255
  int x = id & 7, j = id >> 3;         // XCD, 0..31
  int cb = x * 8 + (j >> 2);           // column block 0..63 (8 per XCD)
  int mt = j & 3;                      // M tile 0..3
  // 3150 total 64-col steps: 14 cbs of 50, 50 cbs of 49
  int start = (cb < 14) ? 50 * cb : 700 + 49 * (cb - 14);
  int nsteps = (cb < 14) ? 50 : 49;
  int q0 = mt * 512;
  int tid = threadIdx.x;
  int wv = tid >> 6, lane = tid & 63;  // wave = row band (64 rows)
  int g = lane >> 4, c0 = lane & 15;   // frag k-group / row-or-col class

  __shared__ __align__(16) unsigned char lds[32768];   // 2 x 16 KB B buffers

  // ---- stage A tile (512 rows x 128 K) in 4 rounds of 32 KB ----
  v8s a[4][4];
#pragma unroll
  for (int c = 0; c < 4; ++c) {
    const char* gbase = (const char*)embB + q0 * 256 + c * 32768;
#pragma unroll
    for (int i = 0; i < 4; ++i) {
      int off = i * 8192 + tid * 16;
      async16(gbase + off, lds + off);
    }
    asm volatile("s_waitcnt vmcnt(0)" ::: "memory");
    __builtin_amdgcn_sched_barrier(0);
    __builtin_amdgcn_s_barrier();
    if ((wv >> 1) == c) {              // this wave's 64 rows live in this chunk
#pragma unroll
      for (int fm = 0; fm < 4; ++fm)
#pragma unroll
        for (int k = 0; k < 4; ++k) {
          int lrow = (wv & 1) * 64 + fm * 16 + c0;   // row within 128-row chunk
          a[fm][k] = *(const v8s*)(lds + lrow * 256 + (((k * 4 + g) ^ c0) << 4));
        }
    }
    asm volatile("s_waitcnt lgkmcnt(0)" ::: "memory");
    __builtin_amdgcn_sched_barrier(0);
    __builtin_amdgcn_s_barrier();
  }

  float m1[16], m2[16], m3[16];
#pragma unroll
  for (int t = 0; t < 16; ++t) { m1[t] = -1e30f; m2[t] = -1e30f; m3[t] = -1e30f; }
  const v4f vzero = {0.f, 0.f, 0.f, 0.f};   // shared acc-init regs, hoisted

  const char* bbase = (const char*)bankB + (size_t)start * 16384;  // 64 cols * 256 B

  // ---- prologue: stage step 0 into buf0 (2 async16/thread = 16 KB/block) ----
#pragma unroll
  for (int i = 0; i < 2; ++i) {
    int off = i * 8192 + tid * 16;
    async16(bbase + off, lds + off);
  }

  const char* gnext = bbase + 16384;   // running pointer: step s+1 source
  for (int s = 0; s < nsteps; ++s) {
    if (s + 1 < nsteps) {
      // issue next-step stage FIRST, then wait only for the current buffer
      unsigned char* ldst = lds + ((s + 1) & 1) * 16384;
#pragma unroll
      for (int i = 0; i < 2; ++i) {
        int off = i * 8192 + tid * 16;
        async16(gnext + off, ldst + off);
      }
      gnext += 16384;
      asm volatile("s_waitcnt vmcnt(2)" ::: "memory");  // prefetch stays in flight
    } else {
      asm volatile("s_waitcnt vmcnt(0)" ::: "memory");  // epilogue: drain last buffer
    }
    __builtin_amdgcn_sched_barrier(0);
    __builtin_amdgcn_s_barrier();                       // buf[cur] ready across waves

    const unsigned char* bp = lds + (s & 1) * 16384;
#pragma unroll
    for (int fn = 0; fn < 4; ++fn) {
      v8s bf[4];
      int col = fn * 16 + c0;
#pragma unroll
      for (int k = 0; k < 4; ++k)
        bf[k] = *(const v8s*)(bp + col * 256 + (((k * 4 + g) ^ c0) << 4));
      v4f acc0 = __builtin_amdgcn_mfma_f32_16x16x32_bf16(a[0][0], bf[0], vzero, 0, 0, 0);
      v4f acc1 = __builtin_amdgcn_mfma_f32_16x16x32_bf16(a[1][0], bf[0], vzero, 0, 0, 0);
      v4f acc2 = __builtin_amdgcn_mfma_f32_16x16x32_bf16(a[2][0], bf[0], vzero, 0, 0, 0);
      v4f acc3 = __builtin_amdgcn_mfma_f32_16x16x32_bf16(a[3][0], bf[0], vzero, 0, 0, 0);
#pragma unroll
      for (int k = 1; k < 4; ++k) {
        acc0 = __builtin_amdgcn_mfma_f32_16x16x32_bf16(a[0][k], bf[k], acc0, 0, 0, 0);
        acc1 = __builtin_amdgcn_mfma_f32_16x16x32_bf16(a[1][k], bf[k], acc1, 0, 0, 0);
        acc2 = __builtin_amdgcn_mfma_f32_16x16x32_bf16(a[2][k], bf[k], acc2, 0, 0, 0);
        acc3 = __builtin_amdgcn_mfma_f32_16x16x32_bf16(a[3][k], bf[k], acc3, 0, 0, 0);
      }
#pragma unroll
      for (int j2 = 0; j2 < 4; ++j2) {   // C/D: row=g*4+j2, col=c0 (within frag)
        insert3(m1[j2],      m2[j2],      m3[j2],      acc0[j2]);
        insert3(m1[4 + j2],  m2[4 + j2],  m3[4 + j2],  acc1[j2]);
        insert3(m1[8 + j2],  m2[8 + j2],  m3[8 + j2],  acc2[j2]);
        insert3(m1[12 + j2], m2[12 + j2], m3[12 + j2], acc3[j2]);
      }
    }
    // all waves done reading buf[cur] before next iteration overwrites it
    __builtin_amdgcn_s_barrier();
  }

  // ---- merge top-3 across the 16 col-class lanes (butterfly) ----
#pragma unroll
  for (int mask = 1; mask < 16; mask <<= 1) {
#pragma unroll
    for (int t = 0; t < 16; ++t) {
      float v1 = __shfl_xor(m1[t], mask);
      float v2 = __shfl_xor(m2[t], mask);
      float v3 = __shfl_xor(m3[t], mask);
      insert3(m1[t], m2[t], m3[t], v1);
      insert3(m1[t], m2[t], m3[t], v2);
      insert3(m1[t], m2[t], m3[t], v3);
    }
  }

  if (c0 == 0) {
#pragma unroll
    for (int t = 0; t < 16; ++t) {       // t = fm*4 + j2
      int q = q0 + wv * 64 + (t >> 2) * 16 + g * 4 + (t & 3);
      float* dst = partial + (size_t)q * NC3 + cb * 3;   // query-major
      dst[0] = m1[t];
      dst[1] = m2[t];
      dst[2] = m3[t];
    }
  }
}

// ---------------- kernel 3: fused final = per-query merge + top-8 mean ------
// one block per image; thread q' owns query b*256+q' (scan 192 partials,
// top-3 -> distance), then in-block top-8 tree over the 256 distances.
__global__ void final_kernel(const float* __restrict__ partial, float* __restrict__ out) {
  int b = blockIdx.x;            // image
  int tid = threadIdx.x;         // patch 0..255
  int q = b * 256 + tid;
  const float* src = partial + (size_t)q * NC3;
  float m1 = -1e30f, m2 = -1e30f, m3 = -1e30f;
  for (int c = 0; c < NC3; ++c) insert3(m1, m2, m3, src[c]);
  float d1 = sqrtf(fmaxf(2.f - 2.f * m1, 0.f));
  float d2 = sqrtf(fmaxf(2.f - 2.f * m2, 0.f));
  float d3 = sqrtf(fmaxf(2.f - 2.f * m3, 0.f));
  float d = (d1 + d2 + d3) * (1.f / 3.f);

  __shared__ float vals[256];
  __shared__ float rv[256];
  __shared__ int ri[256];
  vals[tid] = d;
  __syncthreads();
  float sum = 0.f;
  for (int iter = 0; iter < 8; ++iter) {   // k = ceil(256*0.03) = 8
    rv[tid] = vals[tid]; ri[tid] = tid;
    __syncthreads();
    for (int s = 128; s > 0; s >>= 1) {
      if (tid < s && rv[tid + s] > rv[tid]) { rv[tid] = rv[tid + s]; ri[tid] = ri[tid + s]; }
      __syncthreads();
    }
    sum += rv[0];
    if (tid == 0) vals[ri[0]] = -1e30f;
    __syncthreads();
  }
  if (tid == 0) out[b] = sum * (1.f / 8.f);
}

extern "C" void kernel_launch(void* const* d_in, const int* in_sizes, int n_in,
                              void* d_out, int out_size, void* d_ws, size_t ws_size,
                              hipStream_t stream) {
  const float* fm   = (const float*)d_in[0];   // [8,112,16,16]
  const float* pw   = (const float*)d_in[1];   // [128,112]
  const float* bank = (const float*)d_in[2];   // [200000,128]
  float* out = (float*)d_out;                  // [8]

  char* ws = (char*)d_ws;
  unsigned short* bankB = (unsigned short*)ws;                       // 51,609,600 B
  unsigned short* embB  = (unsigned short*)(ws + 51609600);          //    524,288 B
  float* partial        = (float*)(ws + 51609600 + 524288);          //  1,572,864 B

  prep_kernel<<<PREP_BANK_BLK + PREP_EMB_BLK, 256, 0, stream>>>(fm, pw, bank, embB, bankB);
  sim_top3_kernel<<<256, 512, 0, stream>>>(embB, bankB, partial);
  final_kernel<<<8, 256, 0, stream>>>(partial, out);
}